// Round 14
// baseline (523.094 us; speedup 1.0000x reference)
//
#include <hip/hip_runtime.h>

// Viterbi CRF decode: potentials [B,T,C] f32, transitions [C,C] f32 -> one-hot [B,T,C] f32
// B=256, T=1024, C=128.
//
// r14: ONE fused kernel, 1024 threads / 16 waves (4 per SIMD), 1 block/batch/CU.
//  Phase 1 (fwd, inline asm): max-only DP. Lane (g=l>>4, i=l&15): group G=w*4+g
//   owns c-pair (2G, 2G+1); lane reads p=8i..8i+7 (2x ds_read_b128, 12-stride
//   LDS). 16 T floats/lane pinned in v64-v79. 8 pk_add + 8 max3/max trees into
//   v56/v57, 4 DPP rounds (xor1, xor2, row_half_mirror, row_mirror) give ALL
//   lanes both c-maxes -> single writer lane per group: pk_add with pot pair,
//   ds_write_b64 alpha, global_store_dwordx2 q (PRE-pot max; row 0 = zeros).
//   Pot prefetch: exec-masked buffer_load_dwordx2 into fixed v80-v95, reg
//   rotation, vmcnt(4) once per 4-step body. 16 waves = 4/SIMD hide the
//   barrier->ds_read->tree->write chain that capped 8-wave r12/r13 at ~745cy.
//   Values bit-identical to r12/r13 (same add pairing; max exactly assoc.).
//  Phase 2 (bwd, C; r4-validated): transpose T into LDS; wave 0 chases:
//   M = q_t[tag] via readlane; backpointer = first p with (q+pot)+T == M
//   (bit-exact replay) via ballot+ffs; one-hot overwrites d_out.

typedef float f32x2 __attribute__((ext_vector_type(2)));
typedef unsigned int u32x4 __attribute__((ext_vector_type(4)));

constexpr int NB = 256;
constexpr int NT = 1024;
constexpr int NC = 128;

template <int CTRL>
__device__ __forceinline__ float fmax_dpp(float v) {
  int x = __builtin_amdgcn_update_dpp(__float_as_int(v), __float_as_int(v),
                                      CTRL, 0xF, 0xF, false);
  return fmaxf(v, __int_as_float(x));
}
__device__ __forceinline__ float wave_max_to_lane63(float m) {
  m = fmax_dpp<0x111>(m);  // row_shr:1
  m = fmax_dpp<0x112>(m);  // row_shr:2
  m = fmax_dpp<0x114>(m);  // row_shr:4
  m = fmax_dpp<0x118>(m);  // row_shr:8
  m = fmax_dpp<0x142>(m);  // row_bcast:15
  m = fmax_dpp<0x143>(m);  // row_bcast:31 -> lane63 has full max
  return m;
}

// alpha LDS: p at float index 12*(p>>3)+(p&7) (12-stride layout).
constexpr int ABUF = 192;

#define DPPR2(CTL)                                                         \
  "v_max_f32_dpp v56, v56, v56 " CTL " row_mask:0xf bank_mask:0xf\n\t"     \
  "v_max_f32_dpp v57, v57, v57 " CTL " row_mask:0xf bank_mask:0xf\n\t"

// one DP step: read buf RD, write buf WR, pot pair regs PCP ("80:81"...),
// q-store byte offset SOFF.
#define STEP_S(RD, WR, PCP, SOFF)                                          \
  "ds_read_b128 v[48:51], %[" RD "]\n\t"                                   \
  "ds_read_b128 v[52:55], %[" RD "] offset:16\n\t"                         \
  "s_waitcnt lgkmcnt(0)\n\t"                                               \
  "v_pk_add_f32 v[32:33], v[48:49], v[64:65]\n\t"                          \
  "v_pk_add_f32 v[40:41], v[48:49], v[72:73]\n\t"                          \
  "v_pk_add_f32 v[34:35], v[50:51], v[66:67]\n\t"                          \
  "v_pk_add_f32 v[42:43], v[50:51], v[74:75]\n\t"                          \
  "v_pk_add_f32 v[36:37], v[52:53], v[68:69]\n\t"                          \
  "v_pk_add_f32 v[44:45], v[52:53], v[76:77]\n\t"                          \
  "v_pk_add_f32 v[38:39], v[54:55], v[70:71]\n\t"                          \
  "v_pk_add_f32 v[46:47], v[54:55], v[78:79]\n\t"                          \
  "v_max3_f32 v56, v32, v33, v34\n\t"                                      \
  "v_max3_f32 v57, v40, v41, v42\n\t"                                      \
  "v_max3_f32 v35, v35, v36, v37\n\t"                                      \
  "v_max3_f32 v43, v43, v44, v45\n\t"                                      \
  "v_max3_f32 v56, v56, v35, v38\n\t"                                      \
  "v_max3_f32 v57, v57, v43, v46\n\t"                                      \
  "v_max_f32 v56, v56, v39\n\t"                                            \
  "v_max_f32 v57, v57, v47\n\t"                                            \
  "s_nop 1\n\t"                                                            \
  DPPR2("quad_perm:[1,0,3,2]")                                             \
  "s_nop 0\n\t"                                                            \
  DPPR2("quad_perm:[2,3,0,1]")                                             \
  "s_nop 0\n\t"                                                            \
  DPPR2("row_half_mirror")                                                  \
  "s_nop 0\n\t"                                                            \
  DPPR2("row_mirror")                                                      \
  "s_nop 0\n\t"                                                            \
  "s_mov_b64 exec, %[wmask]\n\t"                                           \
  "v_pk_add_f32 v[58:59], v[56:57], v[" PCP "]\n\t"                        \
  "ds_write_b64 %[" WR "], v[58:59]\n\t"                                   \
  "global_store_dwordx2 %[qoff], v[56:57], %[sout] offset:" SOFF "\n\t"    \
  "s_mov_b64 exec, -1\n\t"                                                 \
  "s_waitcnt lgkmcnt(0)\n\t"                                               \
  "s_barrier\n\t"

// trans load into fixed reg R at byte offset O from toff
#define LDT(R, O) "global_load_dword v" R ", %[toff], %[strans] offset:" O "\n\t"

__global__ __launch_bounds__(1024, 4)
void crf_fused(const float* __restrict__ pot, const float* __restrict__ trans,
               float* __restrict__ out) {
  extern __shared__ __align__(16) float smem[];
  float* alpha = smem;            // 2*ABUF floats (1.5 KB)
  float* tTf = smem + 2 * ABUF;   // 16384 floats (64 KB), phase 2

  const int tid = threadIdx.x;
  const int b = blockIdx.x;
  const int w = tid >> 6;          // wave 0..15
  const int l = tid & 63;          // lane
  const int g = l >> 4;            // 16-lane group-in-wave 0..3
  const int i = l & 15;            // p-chunk (p = 8i..8i+7)
  const int G = w * 4 + g;         // group id 0..63; c-pair (2G, 2G+1)
  const int c0 = 2 * G;
  const bool wr = (i == 0);        // one writer lane per group
  const int widx = 12 * (c0 >> 3) + (c0 & 7);  // c0 LDS idx; c1 = widx+1

  const float* potb = pot + (size_t)b * NT * NC;
  float* outb = out + (size_t)b * NT * NC;

  // ---------------- phase 1: forward DP ----------------
  unsigned rda = (unsigned)(size_t)(alpha + 12 * i);
  unsigned rdb = (unsigned)(size_t)(alpha + ABUF + 12 * i);
  unsigned wra = (unsigned)(size_t)(alpha + widx);
  unsigned wrb = (unsigned)(size_t)(alpha + ABUF + widx);

  // T: v[64+k] = T[8i+k][c0], v[72+k] = T[8i+k][c0+1]  (k = 0..7)
  unsigned toff = (unsigned)((8 * i * NC + c0) * 4);
  unsigned qoff = (unsigned)((1 * NC + c0) * 4);                  // q row 1
  unsigned poff = ((unsigned)b * (NT * NC) + 1 * NC + c0) * 4u;   // pot row 1
  unsigned long long strans = (unsigned long long)(size_t)trans;
  unsigned long long sout = (unsigned long long)(size_t)outb;
  unsigned long long pbase = (unsigned long long)(size_t)pot;
  u32x4 srd;
  srd.x = (unsigned)pbase;
  srd.y = (unsigned)(pbase >> 32) & 0xFFFFu;
  srd.z = (unsigned)(NB * NT * NC) * 4u;     // bounds: OOB load -> 0
  srd.w = 0x00020000u;
  unsigned long long wmask = 0x0001000100010001ull;  // lanes with (l&15)==0
  int cnt = 254;

  if (wr) {
    alpha[widx] = potb[c0];          // alpha_0 = pot[:,0,:]
    alpha[widx + 1] = potb[c0 + 1];
    outb[c0] = 0.0f;                 // q_0 := 0  (alpha_0 = 0 + pot_0)
    outb[c0 + 1] = 0.0f;
  }
  __syncthreads();

  asm volatile(
      // ---- trans -> fixed v64..v79 ----
      LDT("64","0")    LDT("65","512")  LDT("66","1024") LDT("67","1536")
      LDT("68","2048") LDT("69","2560") LDT("70","3072") LDT("71","3584")
      LDT("72","4")    LDT("73","516")  LDT("74","1028") LDT("75","1540")
      LDT("76","2052") LDT("77","2564") LDT("78","3076") LDT("79","3588")
      // ---- pot prefetch rows 1..4 -> v80-87, rows 5..8 -> v88-95 ----
      "s_mov_b64 exec, %[wmask]\n\t"
      "buffer_load_dwordx2 v[80:81], %[poff], %[srd], 0 offen\n\t"
      "buffer_load_dwordx2 v[82:83], %[poff], %[srd], 0 offen offset:512\n\t"
      "buffer_load_dwordx2 v[84:85], %[poff], %[srd], 0 offen offset:1024\n\t"
      "buffer_load_dwordx2 v[86:87], %[poff], %[srd], 0 offen offset:1536\n\t"
      "v_add_u32 %[poff], 0x800, %[poff]\n\t"
      "buffer_load_dwordx2 v[88:89], %[poff], %[srd], 0 offen\n\t"
      "buffer_load_dwordx2 v[90:91], %[poff], %[srd], 0 offen offset:512\n\t"
      "buffer_load_dwordx2 v[92:93], %[poff], %[srd], 0 offen offset:1024\n\t"
      "buffer_load_dwordx2 v[94:95], %[poff], %[srd], 0 offen offset:1536\n\t"
      "v_add_u32 %[poff], 0x800, %[poff]\n\t"
      "s_mov_b64 exec, -1\n\t"
      "s_waitcnt vmcnt(4)\n\t"     // T + rows1-4 resident
      "L_crfmain_%=:\n\t"
      STEP_S("rda", "wrb", "80:81", "0")
      STEP_S("rdb", "wra", "82:83", "512")
      STEP_S("rda", "wrb", "84:85", "1024")
      STEP_S("rdb", "wra", "86:87", "1536")
      "s_waitcnt vmcnt(4)\n\t"     // next 4 pot rows arrived (stores may linger)
      "v_mov_b32 v80, v88\n\t"  "v_mov_b32 v81, v89\n\t"
      "v_mov_b32 v82, v90\n\t"  "v_mov_b32 v83, v91\n\t"
      "v_mov_b32 v84, v92\n\t"  "v_mov_b32 v85, v93\n\t"
      "v_mov_b32 v86, v94\n\t"  "v_mov_b32 v87, v95\n\t"
      "v_add_u32 %[qoff], 0x800, %[qoff]\n\t"
      "s_mov_b64 exec, %[wmask]\n\t"
      "buffer_load_dwordx2 v[88:89], %[poff], %[srd], 0 offen\n\t"
      "buffer_load_dwordx2 v[90:91], %[poff], %[srd], 0 offen offset:512\n\t"
      "buffer_load_dwordx2 v[92:93], %[poff], %[srd], 0 offen offset:1024\n\t"
      "buffer_load_dwordx2 v[94:95], %[poff], %[srd], 0 offen offset:1536\n\t"
      "s_mov_b64 exec, -1\n\t"
      "v_add_u32 %[poff], 0x800, %[poff]\n\t"
      "s_sub_u32 %[cnt], %[cnt], 1\n\t"
      "s_cmp_lg_u32 %[cnt], 0\n\t"
      "s_cbranch_scc1 L_crfmain_%=\n\t"
      // E: t = 1017..1020
      STEP_S("rda", "wrb", "80:81", "0")
      STEP_S("rdb", "wra", "82:83", "512")
      STEP_S("rda", "wrb", "84:85", "1024")
      STEP_S("rdb", "wra", "86:87", "1536")
      "s_waitcnt vmcnt(4)\n\t"
      "v_mov_b32 v80, v88\n\t"  "v_mov_b32 v81, v89\n\t"
      "v_mov_b32 v82, v90\n\t"  "v_mov_b32 v83, v91\n\t"
      "v_mov_b32 v84, v92\n\t"  "v_mov_b32 v85, v93\n\t"
      "v_add_u32 %[qoff], 0x800, %[qoff]\n\t"
      // T: t = 1021..1023
      STEP_S("rda", "wrb", "80:81", "0")
      STEP_S("rdb", "wra", "82:83", "512")
      STEP_S("rda", "wrb", "84:85", "1024")
      "s_waitcnt vmcnt(0)\n\t"
      : [qoff] "+v"(qoff), [poff] "+v"(poff), [cnt] "+s"(cnt)
      : [toff] "v"(toff), [rda] "v"(rda), [rdb] "v"(rdb),
        [wra] "v"(wra), [wrb] "v"(wrb),
        [strans] "s"(strans), [sout] "s"(sout), [srd] "s"(srd),
        [wmask] "s"(wmask)
      : "memory", "scc",
        "v32", "v33", "v34", "v35", "v36", "v37", "v38", "v39",
        "v40", "v41", "v42", "v43", "v44", "v45", "v46", "v47",
        "v48", "v49", "v50", "v51", "v52", "v53", "v54", "v55",
        "v56", "v57", "v58", "v59",
        "v64", "v65", "v66", "v67", "v68", "v69", "v70", "v71",
        "v72", "v73", "v74", "v75", "v76", "v77", "v78", "v79",
        "v80", "v81", "v82", "v83", "v84", "v85", "v86", "v87",
        "v88", "v89", "v90", "v91", "v92", "v93", "v94", "v95");

  // ---------------- phase 2: backward chase ----------------
  __syncthreads();
  {  // transpose trans into LDS: tTp[c][l] = (T[l][c], T[64+l][c]); 1024 thr
    const int rr = tid >> 3;   // source row p 0..127
    const int k8 = tid & 7;    // eighth of the row
    const float4* src = (const float4*)(trans + rr * NC) + k8 * 4;
    const int lo = rr & 63, hb = rr >> 6;
    #pragma unroll
    for (int j = 0; j < 4; ++j) {
      float4 qv = src[j];
      int cb = (k8 * 4 + j) * 4;
      tTf[(cb + 0) * 128 + lo * 2 + hb] = qv.x;
      tTf[(cb + 1) * 128 + lo * 2 + hb] = qv.y;
      tTf[(cb + 2) * 128 + lo * 2 + hb] = qv.z;
      tTf[(cb + 3) * 128 + lo * 2 + hb] = qv.w;
    }
  }
  __syncthreads();
  if (tid >= 64) return;
  const f32x2* tTp = (const f32x2*)tTf;

  // init at t = NT-1: alpha_last = q_last + pot_last; full argmax once
  float qlo_t = outb[(NT - 1) * NC + l];
  float qhi_t = outb[(NT - 1) * NC + 64 + l];
  float alo_t = qlo_t + potb[(NT - 1) * NC + l];
  float ahi_t = qhi_t + potb[(NT - 1) * NC + 64 + l];
  float m0 = wave_max_to_lane63(fmaxf(alo_t, ahi_t));
  float M0 = __int_as_float(__builtin_amdgcn_readlane(__float_as_int(m0), 63));
  unsigned long long bl = __ballot(alo_t == M0);
  unsigned long long bh = __ballot(ahi_t == M0);
  int tag = bl ? (__ffsll((long long)bl) - 1)
               : (64 + __ffsll((long long)bh) - 1);

  // prefetch rows 1022..1015 (q and pot), precompute alpha
  float cqlo[8], cqhi[8], calo[8], cahi[8];
  float nqlo[8], nqhi[8], nplo[8], nphi[8];
  #pragma unroll
  for (int j = 0; j < 8; ++j) {
    int rw = NT - 2 - j;
    cqlo[j] = outb[rw * NC + l];
    cqhi[j] = outb[rw * NC + 64 + l];
    calo[j] = cqlo[j] + potb[rw * NC + l];
    cahi[j] = cqhi[j] + potb[rw * NC + 64 + l];
  }

  for (int g2 = 0; g2 < 128; ++g2) {
    #pragma unroll
    for (int j = 0; j < 8; ++j) {      // prefetch group g2+1
      int rw = NT - 10 - 8 * g2 - j;
      if (rw < 0) rw = 0;
      nqlo[j] = outb[rw * NC + l];
      nqhi[j] = outb[rw * NC + 64 + l];
      nplo[j] = potb[rw * NC + l];
      nphi[j] = potb[rw * NC + 64 + l];
    }
    #pragma unroll
    for (int j = 0; j < 8; ++j) {
      int t = NT - 1 - 8 * g2 - j;
      if (t >= 1) {
        outb[t * NC + l]      = (l == tag) ? 1.0f : 0.0f;
        outb[t * NC + 64 + l] = (64 + l == tag) ? 1.0f : 0.0f;
        int Mlo = __builtin_amdgcn_readlane(__float_as_int(qlo_t), tag & 63);
        int Mhi = __builtin_amdgcn_readlane(__float_as_int(qhi_t), tag & 63);
        float M = __int_as_float((tag < 64) ? Mlo : Mhi);
        f32x2 tt = tTp[tag * 64 + l];
        float vlo = calo[j] + tt.x;
        float vhi = cahi[j] + tt.y;
        unsigned long long el = __ballot(vlo == M);
        unsigned long long eh = __ballot(vhi == M);
        tag = el ? (__ffsll((long long)el) - 1)
                 : (64 + __ffsll((long long)eh) - 1);
        qlo_t = cqlo[j];
        qhi_t = cqhi[j];
      }
    }
    #pragma unroll
    for (int j = 0; j < 8; ++j) {
      cqlo[j] = nqlo[j]; cqhi[j] = nqhi[j];
      calo[j] = nqlo[j] + nplo[j];
      cahi[j] = nqhi[j] + nphi[j];
    }
  }
  outb[l]      = (l == tag) ? 1.0f : 0.0f;
  outb[64 + l] = (64 + l == tag) ? 1.0f : 0.0f;
}

// ---------------- launch ----------------

extern "C" void kernel_launch(void* const* d_in, const int* in_sizes, int n_in,
                              void* d_out, int out_size, void* d_ws, size_t ws_size,
                              hipStream_t stream) {
  const float* pot   = (const float*)d_in[0];
  const float* trans = (const float*)d_in[1];
  float* out = (float*)d_out;

  constexpr int SMEM = (2 * ABUF + NC * NC) * 4;   // 67072 B
  hipFuncSetAttribute((const void*)crf_fused,
                      hipFuncAttributeMaxDynamicSharedMemorySize, SMEM);

  crf_fused<<<NB, 1024, SMEM, stream>>>(pot, trans, out);
}

// Round 15
// 422.726 us; speedup vs baseline: 1.2374x; 1.2374x over previous
//
#include <hip/hip_runtime.h>

// Viterbi CRF decode: potentials [B,T,C] f32, transitions [C,C] f32 -> one-hot [B,T,C] f32
// B=256, T=1024, C=128.
//
// r15 = r13 (best measured: 414 us) + two micro-polishes:
//   (a) tT transpose hoisted BEFORE phase 1 (tTf region is untouched by the
//       fwd asm; rides the existing pre-loop barrier instead of serializing
//       between phases),
//   (b) STEP issues the q global_store before the ds_write (VMEM starts
//       earlier; lgkmcnt(0) covers only the LDS write).
// Structure (validated r9-r14): step = max(DS 384, VALU 346) + ~350 fixed
// (barrier + LDS turnaround); L=8 geometry balances the pipes; B=#CU forces
// 1 batch/CU so wider/narrower wave counts regress (r10: 907, r14: 907-eq).
//
//  Phase 1 (fwd, inline asm): max-only DP. lane (g=l>>3, i=l&7): 16 p/lane
//   (4x ds_read_b128, 12-stride LDS), 2 c/lane (32 T floats pinned v64-v95).
//   Trees: p-halves at lgkmcnt(2)/(0), A/B max3 chains interleaved; 3 DPP
//   rounds (quad_perm xor1/xor2 + row_half_mirror). Writers (l&7)<2 stash
//   q_t (PRE-pot max) to d_out, alpha_t = q_t + pot_t to LDS double-buffer.
//  Phase 2 (bwd, C; r4-validated): wave 0 chases: M = q_t[tag] via readlane;
//   backpointer = first p with (q+pot)+T == M (bit-exact replay of fwd's
//   adds) via ballot+ffs; one-hot overwrites d_out.

typedef float f32x2 __attribute__((ext_vector_type(2)));
typedef unsigned int u32x4 __attribute__((ext_vector_type(4)));

constexpr int NB = 256;
constexpr int NT = 1024;
constexpr int NC = 128;

template <int CTRL>
__device__ __forceinline__ float fmax_dpp(float v) {
  int x = __builtin_amdgcn_update_dpp(__float_as_int(v), __float_as_int(v),
                                      CTRL, 0xF, 0xF, false);
  return fmaxf(v, __int_as_float(x));
}
__device__ __forceinline__ float wave_max_to_lane63(float m) {
  m = fmax_dpp<0x111>(m);  // row_shr:1
  m = fmax_dpp<0x112>(m);  // row_shr:2
  m = fmax_dpp<0x114>(m);  // row_shr:4
  m = fmax_dpp<0x118>(m);  // row_shr:8
  m = fmax_dpp<0x142>(m);  // row_bcast:15
  m = fmax_dpp<0x143>(m);  // row_bcast:31 -> lane63 has full max
  return m;
}

// alpha LDS: p at float index 12*(p>>3)+(p&7) (12-stride layout).
constexpr int ABUF = 192;

#define DPP2(CTL)                                                          \
  "v_max_f32_dpp v32, v32, v32 " CTL " row_mask:0xf bank_mask:0xf\n\t"     \
  "v_max_f32_dpp v96, v96, v96 " CTL " row_mask:0xf bank_mask:0xf\n\t"

// one DP step: read buf RD, write buf WR, pot reg PC, q-store byte offset SOFF.
#define STEP_S(RD, WR, PC, SOFF)                                           \
  "ds_read_b128 v[48:51], %[" RD "]\n\t"                                   \
  "ds_read_b128 v[52:55], %[" RD "] offset:16\n\t"                         \
  "ds_read_b128 v[56:59], %[" RD "] offset:48\n\t"                         \
  "ds_read_b128 v[60:63], %[" RD "] offset:64\n\t"                         \
  "s_waitcnt lgkmcnt(2)\n\t"                                               \
  "v_pk_add_f32 v[32:33], v[48:49], v[64:65]\n\t"                          \
  "v_pk_add_f32 v[96:97], v[48:49], v[80:81]\n\t"                          \
  "v_pk_add_f32 v[34:35], v[50:51], v[66:67]\n\t"                          \
  "v_pk_add_f32 v[98:99], v[50:51], v[82:83]\n\t"                          \
  "v_pk_add_f32 v[36:37], v[52:53], v[68:69]\n\t"                          \
  "v_pk_add_f32 v[100:101], v[52:53], v[84:85]\n\t"                        \
  "v_pk_add_f32 v[38:39], v[54:55], v[70:71]\n\t"                          \
  "v_pk_add_f32 v[102:103], v[54:55], v[86:87]\n\t"                        \
  "v_max3_f32 v32, v32, v33, v34\n\t"                                      \
  "v_max3_f32 v96, v96, v97, v98\n\t"                                      \
  "v_max3_f32 v35, v35, v36, v37\n\t"                                      \
  "v_max3_f32 v99, v99, v100, v101\n\t"                                    \
  "s_waitcnt lgkmcnt(0)\n\t"                                               \
  "v_pk_add_f32 v[40:41], v[56:57], v[72:73]\n\t"                          \
  "v_pk_add_f32 v[104:105], v[56:57], v[88:89]\n\t"                        \
  "v_pk_add_f32 v[42:43], v[58:59], v[74:75]\n\t"                          \
  "v_pk_add_f32 v[106:107], v[58:59], v[90:91]\n\t"                        \
  "v_pk_add_f32 v[44:45], v[60:61], v[76:77]\n\t"                          \
  "v_pk_add_f32 v[108:109], v[60:61], v[92:93]\n\t"                        \
  "v_pk_add_f32 v[46:47], v[62:63], v[78:79]\n\t"                          \
  "v_pk_add_f32 v[110:111], v[62:63], v[94:95]\n\t"                        \
  "v_max3_f32 v38, v38, v39, v40\n\t"                                      \
  "v_max3_f32 v102, v102, v103, v104\n\t"                                  \
  "v_max3_f32 v41, v41, v42, v43\n\t"                                      \
  "v_max3_f32 v105, v105, v106, v107\n\t"                                  \
  "v_max3_f32 v44, v44, v45, v46\n\t"                                      \
  "v_max3_f32 v108, v108, v109, v110\n\t"                                  \
  "v_max3_f32 v32, v32, v35, v38\n\t"                                      \
  "v_max3_f32 v96, v96, v99, v102\n\t"                                     \
  "v_max3_f32 v41, v41, v44, v47\n\t"                                      \
  "v_max3_f32 v105, v105, v108, v111\n\t"                                  \
  "v_max_f32 v32, v32, v41\n\t"                                            \
  "v_max_f32 v96, v96, v105\n\t"                                           \
  "s_nop 1\n\t"                                                            \
  DPP2("quad_perm:[1,0,3,2]")                                              \
  "s_nop 0\n\t"                                                            \
  DPP2("quad_perm:[2,3,0,1]")                                              \
  "s_nop 0\n\t"                                                            \
  DPP2("row_half_mirror")                                                  \
  "s_nop 0\n\t"                                                            \
  "v_cndmask_b32 v41, v32, v96, %[selb0]\n\t"                              \
  "s_mov_b64 exec, %[wmask]\n\t"                                           \
  "global_store_dword %[qoff], v41, %[sout] offset:" SOFF "\n\t"           \
  "v_add_f32 v40, v41, %[" PC "]\n\t"                                      \
  "ds_write_b32 %[" WR "], v40\n\t"                                        \
  "s_mov_b64 exec, -1\n\t"                                                 \
  "s_waitcnt lgkmcnt(0)\n\t"                                               \
  "s_barrier\n\t"

// trans load into fixed reg R at byte offset O from toff/toff2
#define LDT(R, B, O) "global_load_dword v" R ", %[" B "], %[strans] offset:" O "\n\t"

__global__ __launch_bounds__(512)
void crf_fused(const float* __restrict__ pot, const float* __restrict__ trans,
               float* __restrict__ out) {
  extern __shared__ __align__(16) float smem[];
  float* alpha = smem;            // 2*ABUF floats (1.5 KB)
  float* tTf = smem + 2 * ABUF;   // 16384 floats (64 KB), phase 2

  const int tid = threadIdx.x;
  const int b = blockIdx.x;
  const int w = tid >> 6;          // wave 0..7
  const int l = tid & 63;          // lane
  const int g = l >> 3;            // 8-lane group 0..7
  const int i = l & 7;             // p-chunk (p = 16i..16i+15)
  const int G = w * 8 + g;         // c-pair index 0..63 (c0 = 2G)
  const bool wr = (l & 7) < 2;     // writer lanes: (l&7)==0 -> c0, ==1 -> c1
  const int cw = 16 * w + 2 * g + (l & 1);     // writer's c (valid all lanes)
  const int widx = 12 * (cw >> 3) + (cw & 7);  // writer's LDS float index

  const float* potb = pot + (size_t)b * NT * NC;
  float* outb = out + (size_t)b * NT * NC;

  // ---------------- phase 1: forward DP ----------------
  unsigned rda = (unsigned)(size_t)(alpha + 24 * i);
  unsigned rdb = (unsigned)(size_t)(alpha + ABUF + 24 * i);
  unsigned wra = (unsigned)(size_t)(alpha + widx);
  unsigned wrb = (unsigned)(size_t)(alpha + ABUF + widx);

  // trans: v[64+j] = T[16i+j][c0] (j=0..7), v[72+j] = T[16i+8+j][c0];
  //        v[80..95] same for column c0+1.   (c0 = 2G)
  unsigned toff  = (unsigned)((16 * i * NC + 2 * G) * 4);
  unsigned toff2 = toff + 4096;
  unsigned qoff = (unsigned)((1 * NC + cw) * 4);                 // q row 1
  unsigned poff = ((unsigned)b * (NT * NC) + 5 * NC + cw) * 4u;  // pot row 5
  unsigned long long strans = (unsigned long long)(size_t)trans;
  unsigned long long sout = (unsigned long long)(size_t)outb;
  unsigned long long pbase = (unsigned long long)(size_t)pot;
  u32x4 srd;
  srd.x = (unsigned)pbase;
  srd.y = (unsigned)(pbase >> 32) & 0xFFFFu;
  srd.z = (unsigned)(NB * NT * NC) * 4u;     // bounds: OOB load -> 0
  srd.w = 0x00020000u;
  unsigned long long selb0 = 0xAAAAAAAAAAAAAAAAull;  // lanes with l&1
  unsigned long long wmask = 0x0303030303030303ull;  // lanes with (l&7)<2
  int cnt = 254;

  float pc0 = potb[1 * NC + cw], pc1 = potb[2 * NC + cw];
  float pc2 = potb[3 * NC + cw], pc3 = potb[4 * NC + cw];
  float pn0 = 0.f, pn1 = 0.f, pn2 = 0.f, pn3 = 0.f;

  // tT transpose HOISTED here (phase-1 asm never touches tTf):
  // tTp[c][l2] = (T[l2][c], T[64+l2][c])
  {
    const int rr = tid >> 2;   // source row p 0..127
    const int q4 = tid & 3;    // quarter of the row
    const float4* src = (const float4*)(trans + rr * NC + q4 * 32);
    const int lo = rr & 63, hb = rr >> 6;
    #pragma unroll
    for (int j = 0; j < 8; ++j) {
      float4 qv = src[j];
      int cb = q4 * 32 + 4 * j;
      tTf[(cb + 0) * 128 + lo * 2 + hb] = qv.x;
      tTf[(cb + 1) * 128 + lo * 2 + hb] = qv.y;
      tTf[(cb + 2) * 128 + lo * 2 + hb] = qv.z;
      tTf[(cb + 3) * 128 + lo * 2 + hb] = qv.w;
    }
  }
  if (wr) {
    alpha[widx] = potb[cw];   // alpha_0 = pot[:,0,:]
    outb[cw] = 0.0f;          // q_0 := 0  (alpha_0 = 0 + pot_0)
  }
  __syncthreads();

  asm volatile(
      // ---- trans -> fixed v64..v95 ----
      LDT("64","toff","0")     LDT("65","toff","512")
      LDT("66","toff","1024")  LDT("67","toff","1536")
      LDT("68","toff","2048")  LDT("69","toff","2560")
      LDT("70","toff","3072")  LDT("71","toff","3584")
      LDT("72","toff2","0")    LDT("73","toff2","512")
      LDT("74","toff2","1024") LDT("75","toff2","1536")
      LDT("76","toff2","2048") LDT("77","toff2","2560")
      LDT("78","toff2","3072") LDT("79","toff2","3584")
      LDT("80","toff","4")     LDT("81","toff","516")
      LDT("82","toff","1028")  LDT("83","toff","1540")
      LDT("84","toff","2052")  LDT("85","toff","2564")
      LDT("86","toff","3076")  LDT("87","toff","3588")
      LDT("88","toff2","4")    LDT("89","toff2","516")
      LDT("90","toff2","1028") LDT("91","toff2","1540")
      LDT("92","toff2","2052") LDT("93","toff2","2564")
      LDT("94","toff2","3076") LDT("95","toff2","3588")
      "s_waitcnt vmcnt(0)\n\t"
      // ---- pot prefetch rows 5..8 ----
      "buffer_load_dword %[pn0], %[poff], %[srd], 0 offen\n\t"
      "buffer_load_dword %[pn1], %[poff], %[srd], 0 offen offset:512\n\t"
      "buffer_load_dword %[pn2], %[poff], %[srd], 0 offen offset:1024\n\t"
      "buffer_load_dword %[pn3], %[poff], %[srd], 0 offen offset:1536\n\t"
      "L_crfmain_%=:\n\t"
      STEP_S("rda", "wrb", "pc0", "0")
      STEP_S("rdb", "wra", "pc1", "512")
      STEP_S("rda", "wrb", "pc2", "1024")
      STEP_S("rdb", "wra", "pc3", "1536")
      "s_waitcnt vmcnt(4)\n\t"
      "v_mov_b32 %[pc0], %[pn0]\n\t"
      "v_mov_b32 %[pc1], %[pn1]\n\t"
      "v_mov_b32 %[pc2], %[pn2]\n\t"
      "v_mov_b32 %[pc3], %[pn3]\n\t"
      "v_add_u32 %[poff], 0x800, %[poff]\n\t"
      "v_add_u32 %[qoff], 0x800, %[qoff]\n\t"
      "buffer_load_dword %[pn0], %[poff], %[srd], 0 offen\n\t"
      "buffer_load_dword %[pn1], %[poff], %[srd], 0 offen offset:512\n\t"
      "buffer_load_dword %[pn2], %[poff], %[srd], 0 offen offset:1024\n\t"
      "buffer_load_dword %[pn3], %[poff], %[srd], 0 offen offset:1536\n\t"
      "s_sub_u32 %[cnt], %[cnt], 1\n\t"
      "s_cmp_lg_u32 %[cnt], 0\n\t"
      "s_cbranch_scc1 L_crfmain_%=\n\t"
      // E: t = 1017..1020
      STEP_S("rda", "wrb", "pc0", "0")
      STEP_S("rdb", "wra", "pc1", "512")
      STEP_S("rda", "wrb", "pc2", "1024")
      STEP_S("rdb", "wra", "pc3", "1536")
      "s_waitcnt vmcnt(4)\n\t"
      "v_mov_b32 %[pc0], %[pn0]\n\t"
      "v_mov_b32 %[pc1], %[pn1]\n\t"
      "v_mov_b32 %[pc2], %[pn2]\n\t"
      "v_add_u32 %[qoff], 0x800, %[qoff]\n\t"
      // T: t = 1021..1023
      STEP_S("rda", "wrb", "pc0", "0")
      STEP_S("rdb", "wra", "pc1", "512")
      STEP_S("rda", "wrb", "pc2", "1024")
      "s_waitcnt vmcnt(0)\n\t"
      : [pc0] "+v"(pc0), [pc1] "+v"(pc1), [pc2] "+v"(pc2), [pc3] "+v"(pc3),
        [pn0] "+v"(pn0), [pn1] "+v"(pn1), [pn2] "+v"(pn2), [pn3] "+v"(pn3),
        [qoff] "+v"(qoff), [poff] "+v"(poff), [cnt] "+s"(cnt)
      : [toff] "v"(toff), [toff2] "v"(toff2),
        [rda] "v"(rda), [rdb] "v"(rdb), [wra] "v"(wra), [wrb] "v"(wrb),
        [strans] "s"(strans), [sout] "s"(sout), [srd] "s"(srd),
        [selb0] "s"(selb0), [wmask] "s"(wmask)
      : "memory", "scc",
        "v32", "v33", "v34", "v35", "v36", "v37", "v38", "v39",
        "v40", "v41", "v42", "v43", "v44", "v45", "v46", "v47",
        "v48", "v49", "v50", "v51", "v52", "v53", "v54", "v55",
        "v56", "v57", "v58", "v59", "v60", "v61", "v62", "v63",
        "v64", "v65", "v66", "v67", "v68", "v69", "v70", "v71",
        "v72", "v73", "v74", "v75", "v76", "v77", "v78", "v79",
        "v80", "v81", "v82", "v83", "v84", "v85", "v86", "v87",
        "v88", "v89", "v90", "v91", "v92", "v93", "v94", "v95",
        "v96", "v97", "v98", "v99", "v100", "v101", "v102", "v103",
        "v104", "v105", "v106", "v107", "v108", "v109", "v110", "v111");

  // ---------------- phase 2: backward chase ----------------
  // (tT already transposed before phase 1; barriers inside the asm preserved it)
  if (tid >= 64) return;
  const f32x2* tTp = (const f32x2*)tTf;

  // init at t = NT-1: alpha_last = q_last + pot_last; full argmax once
  float qlo_t = outb[(NT - 1) * NC + l];
  float qhi_t = outb[(NT - 1) * NC + 64 + l];
  float alo_t = qlo_t + potb[(NT - 1) * NC + l];
  float ahi_t = qhi_t + potb[(NT - 1) * NC + 64 + l];
  float m0 = wave_max_to_lane63(fmaxf(alo_t, ahi_t));
  float M0 = __int_as_float(__builtin_amdgcn_readlane(__float_as_int(m0), 63));
  unsigned long long bl = __ballot(alo_t == M0);
  unsigned long long bh = __ballot(ahi_t == M0);
  int tag = bl ? (__ffsll((long long)bl) - 1)
               : (64 + __ffsll((long long)bh) - 1);

  // prefetch rows 1022..1015 (q and pot), precompute alpha
  float cqlo[8], cqhi[8], calo[8], cahi[8];
  float nqlo[8], nqhi[8], nplo[8], nphi[8];
  #pragma unroll
  for (int j = 0; j < 8; ++j) {
    int rw = NT - 2 - j;
    cqlo[j] = outb[rw * NC + l];
    cqhi[j] = outb[rw * NC + 64 + l];
    calo[j] = cqlo[j] + potb[rw * NC + l];
    cahi[j] = cqhi[j] + potb[rw * NC + 64 + l];
  }

  for (int g2 = 0; g2 < 128; ++g2) {
    #pragma unroll
    for (int j = 0; j < 8; ++j) {      // prefetch group g2+1
      int rw = NT - 10 - 8 * g2 - j;
      if (rw < 0) rw = 0;
      nqlo[j] = outb[rw * NC + l];
      nqhi[j] = outb[rw * NC + 64 + l];
      nplo[j] = potb[rw * NC + l];
      nphi[j] = potb[rw * NC + 64 + l];
    }
    #pragma unroll
    for (int j = 0; j < 8; ++j) {
      int t = NT - 1 - 8 * g2 - j;
      if (t >= 1) {
        outb[t * NC + l]      = (l == tag) ? 1.0f : 0.0f;
        outb[t * NC + 64 + l] = (64 + l == tag) ? 1.0f : 0.0f;
        int Mlo = __builtin_amdgcn_readlane(__float_as_int(qlo_t), tag & 63);
        int Mhi = __builtin_amdgcn_readlane(__float_as_int(qhi_t), tag & 63);
        float M = __int_as_float((tag < 64) ? Mlo : Mhi);
        f32x2 tt = tTp[tag * 64 + l];
        float vlo = calo[j] + tt.x;
        float vhi = cahi[j] + tt.y;
        unsigned long long el = __ballot(vlo == M);
        unsigned long long eh = __ballot(vhi == M);
        tag = el ? (__ffsll((long long)el) - 1)
                 : (64 + __ffsll((long long)eh) - 1);
        qlo_t = cqlo[j];
        qhi_t = cqhi[j];
      }
    }
    #pragma unroll
    for (int j = 0; j < 8; ++j) {
      cqlo[j] = nqlo[j]; cqhi[j] = nqhi[j];
      calo[j] = nqlo[j] + nplo[j];
      cahi[j] = nqhi[j] + nphi[j];
    }
  }
  outb[l]      = (l == tag) ? 1.0f : 0.0f;
  outb[64 + l] = (64 + l == tag) ? 1.0f : 0.0f;
}

// ---------------- launch ----------------

extern "C" void kernel_launch(void* const* d_in, const int* in_sizes, int n_in,
                              void* d_out, int out_size, void* d_ws, size_t ws_size,
                              hipStream_t stream) {
  const float* pot   = (const float*)d_in[0];
  const float* trans = (const float*)d_in[1];
  float* out = (float*)d_out;

  constexpr int SMEM = (2 * ABUF + NC * NC) * 4;   // 67072 B
  hipFuncSetAttribute((const void*)crf_fused,
                      hipFuncAttributeMaxDynamicSharedMemorySize, SMEM);

  crf_fused<<<NB, 512, SMEM, stream>>>(pot, trans, out);
}

// Round 16
// 414.356 us; speedup vs baseline: 1.2624x; 1.0202x over previous
//
#include <hip/hip_runtime.h>

// Viterbi CRF decode: potentials [B,T,C] f32, transitions [C,C] f32 -> one-hot [B,T,C] f32
// B=256, T=1024, C=128.
//
// r16 = EXACT revert to r13 (best measured: 414.0 us e2e / 446.5 us dispatch).
// r15's micro-polishes (transpose hoist, store-before-ds_write) regressed +6us:
// the ds_write sits on the critical barrier path; the q global_store drains in
// the next step's shadow. Structural floor (validated r9-r15):
//   step = max(DS ~384, VALU ~346) + ~350 fixed (barrier + LDS turnaround)
//   fwd = 1023 x 745cyc / 2.4GHz ~ 317us; bwd chase ~95us; total ~412us.
// Escapes eliminated: 16-wave (r14: 907-eq), 1-wave/SIMD (r10: 907), parallel
// max-plus scan (256x FLOPs), inline argmax (r1/r2: net negative), multi-batch
// blocks (B = #CUs).
//
//  Phase 1 (fwd, inline asm): max-only DP, L=8 groups: lane (g=l>>3, i=l&7):
//   16 p/lane (4x ds_read_b128, 12-stride LDS), 2 c/lane (32 T floats pinned
//   in v64-v95). Trees split into p-halves at lgkmcnt(2)/(0); A/B max3 chains
//   pairwise interleaved. 3 DPP rounds (quad_perm xor1/xor2 + row_half_mirror).
//   Writers (l&7)<2 stash q_t (PRE-pot max) to d_out and alpha_t = q_t + pot_t
//   to the LDS double-buffer.
//  Phase 2 (bwd, C; r4-validated): transpose T into LDS; wave 0 chases:
//   M = q_t[tag] via readlane; backpointer = first p with (q+pot)+T == M
//   (bit-exact replay of fwd's adds) via ballot+ffs; one-hot overwrites d_out.

typedef float f32x2 __attribute__((ext_vector_type(2)));
typedef unsigned int u32x4 __attribute__((ext_vector_type(4)));

constexpr int NB = 256;
constexpr int NT = 1024;
constexpr int NC = 128;

template <int CTRL>
__device__ __forceinline__ float fmax_dpp(float v) {
  int x = __builtin_amdgcn_update_dpp(__float_as_int(v), __float_as_int(v),
                                      CTRL, 0xF, 0xF, false);
  return fmaxf(v, __int_as_float(x));
}
__device__ __forceinline__ float wave_max_to_lane63(float m) {
  m = fmax_dpp<0x111>(m);  // row_shr:1
  m = fmax_dpp<0x112>(m);  // row_shr:2
  m = fmax_dpp<0x114>(m);  // row_shr:4
  m = fmax_dpp<0x118>(m);  // row_shr:8
  m = fmax_dpp<0x142>(m);  // row_bcast:15
  m = fmax_dpp<0x143>(m);  // row_bcast:31 -> lane63 has full max
  return m;
}

// ---------------- forward ----------------
// alpha LDS: p at float index 12*(p>>3)+(p&7) (12-stride layout).
constexpr int ABUF = 192;

#define DPP2(CTL)                                                          \
  "v_max_f32_dpp v32, v32, v32 " CTL " row_mask:0xf bank_mask:0xf\n\t"     \
  "v_max_f32_dpp v96, v96, v96 " CTL " row_mask:0xf bank_mask:0xf\n\t"

// one DP step: read buf RD, write buf WR, pot reg PC, q-store byte offset SOFF.
// Trees interleaved A/B and split by p-halves; half-1 starts at lgkmcnt(2).
#define STEP_S(RD, WR, PC, SOFF)                                           \
  "ds_read_b128 v[48:51], %[" RD "]\n\t"                                   \
  "ds_read_b128 v[52:55], %[" RD "] offset:16\n\t"                         \
  "ds_read_b128 v[56:59], %[" RD "] offset:48\n\t"                         \
  "ds_read_b128 v[60:63], %[" RD "] offset:64\n\t"                         \
  "s_waitcnt lgkmcnt(2)\n\t"                                               \
  "v_pk_add_f32 v[32:33], v[48:49], v[64:65]\n\t"                          \
  "v_pk_add_f32 v[96:97], v[48:49], v[80:81]\n\t"                          \
  "v_pk_add_f32 v[34:35], v[50:51], v[66:67]\n\t"                          \
  "v_pk_add_f32 v[98:99], v[50:51], v[82:83]\n\t"                          \
  "v_pk_add_f32 v[36:37], v[52:53], v[68:69]\n\t"                          \
  "v_pk_add_f32 v[100:101], v[52:53], v[84:85]\n\t"                        \
  "v_pk_add_f32 v[38:39], v[54:55], v[70:71]\n\t"                          \
  "v_pk_add_f32 v[102:103], v[54:55], v[86:87]\n\t"                        \
  "v_max3_f32 v32, v32, v33, v34\n\t"                                      \
  "v_max3_f32 v96, v96, v97, v98\n\t"                                      \
  "v_max3_f32 v35, v35, v36, v37\n\t"                                      \
  "v_max3_f32 v99, v99, v100, v101\n\t"                                    \
  "s_waitcnt lgkmcnt(0)\n\t"                                               \
  "v_pk_add_f32 v[40:41], v[56:57], v[72:73]\n\t"                          \
  "v_pk_add_f32 v[104:105], v[56:57], v[88:89]\n\t"                        \
  "v_pk_add_f32 v[42:43], v[58:59], v[74:75]\n\t"                          \
  "v_pk_add_f32 v[106:107], v[58:59], v[90:91]\n\t"                        \
  "v_pk_add_f32 v[44:45], v[60:61], v[76:77]\n\t"                          \
  "v_pk_add_f32 v[108:109], v[60:61], v[92:93]\n\t"                        \
  "v_pk_add_f32 v[46:47], v[62:63], v[78:79]\n\t"                          \
  "v_pk_add_f32 v[110:111], v[62:63], v[94:95]\n\t"                        \
  "v_max3_f32 v38, v38, v39, v40\n\t"                                      \
  "v_max3_f32 v102, v102, v103, v104\n\t"                                  \
  "v_max3_f32 v41, v41, v42, v43\n\t"                                      \
  "v_max3_f32 v105, v105, v106, v107\n\t"                                  \
  "v_max3_f32 v44, v44, v45, v46\n\t"                                      \
  "v_max3_f32 v108, v108, v109, v110\n\t"                                  \
  "v_max3_f32 v32, v32, v35, v38\n\t"                                      \
  "v_max3_f32 v96, v96, v99, v102\n\t"                                     \
  "v_max3_f32 v41, v41, v44, v47\n\t"                                      \
  "v_max3_f32 v105, v105, v108, v111\n\t"                                  \
  "v_max_f32 v32, v32, v41\n\t"                                            \
  "v_max_f32 v96, v96, v105\n\t"                                           \
  "s_nop 1\n\t"                                                            \
  DPP2("quad_perm:[1,0,3,2]")                                              \
  "s_nop 0\n\t"                                                            \
  DPP2("quad_perm:[2,3,0,1]")                                              \
  "s_nop 0\n\t"                                                            \
  DPP2("row_half_mirror")                                                  \
  "s_nop 0\n\t"                                                            \
  "v_cndmask_b32 v41, v32, v96, %[selb0]\n\t"                              \
  "s_mov_b64 exec, %[wmask]\n\t"                                           \
  "v_add_f32 v40, v41, %[" PC "]\n\t"                                      \
  "ds_write_b32 %[" WR "], v40\n\t"                                        \
  "global_store_dword %[qoff], v41, %[sout] offset:" SOFF "\n\t"           \
  "s_mov_b64 exec, -1\n\t"                                                 \
  "s_waitcnt lgkmcnt(0)\n\t"                                               \
  "s_barrier\n\t"

// trans load into fixed reg R at byte offset O from toff/toff2
#define LDT(R, B, O) "global_load_dword v" R ", %[" B "], %[strans] offset:" O "\n\t"

__global__ __launch_bounds__(512)
void crf_fused(const float* __restrict__ pot, const float* __restrict__ trans,
               float* __restrict__ out) {
  extern __shared__ __align__(16) float smem[];
  float* alpha = smem;            // 2*ABUF floats (1.5 KB)
  float* tTf = smem + 2 * ABUF;   // 16384 floats (64 KB), phase 2

  const int tid = threadIdx.x;
  const int b = blockIdx.x;
  const int w = tid >> 6;          // wave 0..7
  const int l = tid & 63;          // lane
  const int g = l >> 3;            // 8-lane group 0..7
  const int i = l & 7;             // p-chunk (p = 16i..16i+15)
  const int G = w * 8 + g;         // c-pair index 0..63 (c0 = 2G)
  const bool wr = (l & 7) < 2;     // writer lanes: (l&7)==0 -> c0, ==1 -> c1
  const int cw = 16 * w + 2 * g + (l & 1);     // writer's c (valid all lanes)
  const int widx = 12 * (cw >> 3) + (cw & 7);  // writer's LDS float index

  const float* potb = pot + (size_t)b * NT * NC;
  float* outb = out + (size_t)b * NT * NC;

  // ---------------- phase 1: forward DP ----------------
  unsigned rda = (unsigned)(size_t)(alpha + 24 * i);
  unsigned rdb = (unsigned)(size_t)(alpha + ABUF + 24 * i);
  unsigned wra = (unsigned)(size_t)(alpha + widx);
  unsigned wrb = (unsigned)(size_t)(alpha + ABUF + widx);

  // trans: v[64+j] = T[16i+j][c0] (j=0..7), v[72+j] = T[16i+8+j][c0];
  //        v[80..95] same for column c0+1.   (c0 = 2G)
  unsigned toff  = (unsigned)((16 * i * NC + 2 * G) * 4);
  unsigned toff2 = toff + 4096;
  unsigned qoff = (unsigned)((1 * NC + cw) * 4);                 // q row 1
  unsigned poff = ((unsigned)b * (NT * NC) + 5 * NC + cw) * 4u;  // pot row 5
  unsigned long long strans = (unsigned long long)(size_t)trans;
  unsigned long long sout = (unsigned long long)(size_t)outb;
  unsigned long long pbase = (unsigned long long)(size_t)pot;
  u32x4 srd;
  srd.x = (unsigned)pbase;
  srd.y = (unsigned)(pbase >> 32) & 0xFFFFu;
  srd.z = (unsigned)(NB * NT * NC) * 4u;     // bounds: OOB load -> 0
  srd.w = 0x00020000u;
  unsigned long long selb0 = 0xAAAAAAAAAAAAAAAAull;  // lanes with l&1
  unsigned long long wmask = 0x0303030303030303ull;  // lanes with (l&7)<2
  int cnt = 254;

  float pc0 = potb[1 * NC + cw], pc1 = potb[2 * NC + cw];
  float pc2 = potb[3 * NC + cw], pc3 = potb[4 * NC + cw];
  float pn0 = 0.f, pn1 = 0.f, pn2 = 0.f, pn3 = 0.f;

  if (wr) {
    alpha[widx] = potb[cw];   // alpha_0 = pot[:,0,:]
    outb[cw] = 0.0f;          // q_0 := 0  (alpha_0 = 0 + pot_0)
  }
  __syncthreads();

  asm volatile(
      // ---- trans -> fixed v64..v95 ----
      LDT("64","toff","0")     LDT("65","toff","512")
      LDT("66","toff","1024")  LDT("67","toff","1536")
      LDT("68","toff","2048")  LDT("69","toff","2560")
      LDT("70","toff","3072")  LDT("71","toff","3584")
      LDT("72","toff2","0")    LDT("73","toff2","512")
      LDT("74","toff2","1024") LDT("75","toff2","1536")
      LDT("76","toff2","2048") LDT("77","toff2","2560")
      LDT("78","toff2","3072") LDT("79","toff2","3584")
      LDT("80","toff","4")     LDT("81","toff","516")
      LDT("82","toff","1028")  LDT("83","toff","1540")
      LDT("84","toff","2052")  LDT("85","toff","2564")
      LDT("86","toff","3076")  LDT("87","toff","3588")
      LDT("88","toff2","4")    LDT("89","toff2","516")
      LDT("90","toff2","1028") LDT("91","toff2","1540")
      LDT("92","toff2","2052") LDT("93","toff2","2564")
      LDT("94","toff2","3076") LDT("95","toff2","3588")
      "s_waitcnt vmcnt(0)\n\t"
      // ---- pot prefetch rows 5..8 ----
      "buffer_load_dword %[pn0], %[poff], %[srd], 0 offen\n\t"
      "buffer_load_dword %[pn1], %[poff], %[srd], 0 offen offset:512\n\t"
      "buffer_load_dword %[pn2], %[poff], %[srd], 0 offen offset:1024\n\t"
      "buffer_load_dword %[pn3], %[poff], %[srd], 0 offen offset:1536\n\t"
      "L_crfmain_%=:\n\t"
      STEP_S("rda", "wrb", "pc0", "0")
      STEP_S("rdb", "wra", "pc1", "512")
      STEP_S("rda", "wrb", "pc2", "1024")
      STEP_S("rdb", "wra", "pc3", "1536")
      "s_waitcnt vmcnt(4)\n\t"
      "v_mov_b32 %[pc0], %[pn0]\n\t"
      "v_mov_b32 %[pc1], %[pn1]\n\t"
      "v_mov_b32 %[pc2], %[pn2]\n\t"
      "v_mov_b32 %[pc3], %[pn3]\n\t"
      "v_add_u32 %[poff], 0x800, %[poff]\n\t"
      "v_add_u32 %[qoff], 0x800, %[qoff]\n\t"
      "buffer_load_dword %[pn0], %[poff], %[srd], 0 offen\n\t"
      "buffer_load_dword %[pn1], %[poff], %[srd], 0 offen offset:512\n\t"
      "buffer_load_dword %[pn2], %[poff], %[srd], 0 offen offset:1024\n\t"
      "buffer_load_dword %[pn3], %[poff], %[srd], 0 offen offset:1536\n\t"
      "s_sub_u32 %[cnt], %[cnt], 1\n\t"
      "s_cmp_lg_u32 %[cnt], 0\n\t"
      "s_cbranch_scc1 L_crfmain_%=\n\t"
      // E: t = 1017..1020
      STEP_S("rda", "wrb", "pc0", "0")
      STEP_S("rdb", "wra", "pc1", "512")
      STEP_S("rda", "wrb", "pc2", "1024")
      STEP_S("rdb", "wra", "pc3", "1536")
      "s_waitcnt vmcnt(4)\n\t"
      "v_mov_b32 %[pc0], %[pn0]\n\t"
      "v_mov_b32 %[pc1], %[pn1]\n\t"
      "v_mov_b32 %[pc2], %[pn2]\n\t"
      "v_add_u32 %[qoff], 0x800, %[qoff]\n\t"
      // T: t = 1021..1023
      STEP_S("rda", "wrb", "pc0", "0")
      STEP_S("rdb", "wra", "pc1", "512")
      STEP_S("rda", "wrb", "pc2", "1024")
      "s_waitcnt vmcnt(0)\n\t"
      : [pc0] "+v"(pc0), [pc1] "+v"(pc1), [pc2] "+v"(pc2), [pc3] "+v"(pc3),
        [pn0] "+v"(pn0), [pn1] "+v"(pn1), [pn2] "+v"(pn2), [pn3] "+v"(pn3),
        [qoff] "+v"(qoff), [poff] "+v"(poff), [cnt] "+s"(cnt)
      : [toff] "v"(toff), [toff2] "v"(toff2),
        [rda] "v"(rda), [rdb] "v"(rdb), [wra] "v"(wra), [wrb] "v"(wrb),
        [strans] "s"(strans), [sout] "s"(sout), [srd] "s"(srd),
        [selb0] "s"(selb0), [wmask] "s"(wmask)
      : "memory", "scc",
        "v32", "v33", "v34", "v35", "v36", "v37", "v38", "v39",
        "v40", "v41", "v42", "v43", "v44", "v45", "v46", "v47",
        "v48", "v49", "v50", "v51", "v52", "v53", "v54", "v55",
        "v56", "v57", "v58", "v59", "v60", "v61", "v62", "v63",
        "v64", "v65", "v66", "v67", "v68", "v69", "v70", "v71",
        "v72", "v73", "v74", "v75", "v76", "v77", "v78", "v79",
        "v80", "v81", "v82", "v83", "v84", "v85", "v86", "v87",
        "v88", "v89", "v90", "v91", "v92", "v93", "v94", "v95",
        "v96", "v97", "v98", "v99", "v100", "v101", "v102", "v103",
        "v104", "v105", "v106", "v107", "v108", "v109", "v110", "v111");

  // ---------------- phase 2: backward chase ----------------
  __syncthreads();
  {  // transpose trans into LDS: tTp[c][l] = (T[l][c], T[64+l][c]); 512 threads
    const int rr = tid >> 2;   // source row p 0..127
    const int q4 = tid & 3;    // quarter of the row
    const float4* src = (const float4*)(trans + rr * NC + q4 * 32);
    const int lo = rr & 63, hb = rr >> 6;
    #pragma unroll
    for (int j = 0; j < 8; ++j) {
      float4 qv = src[j];
      int cb = q4 * 32 + 4 * j;
      tTf[(cb + 0) * 128 + lo * 2 + hb] = qv.x;
      tTf[(cb + 1) * 128 + lo * 2 + hb] = qv.y;
      tTf[(cb + 2) * 128 + lo * 2 + hb] = qv.z;
      tTf[(cb + 3) * 128 + lo * 2 + hb] = qv.w;
    }
  }
  __syncthreads();
  if (tid >= 64) return;
  const f32x2* tTp = (const f32x2*)tTf;

  // init at t = NT-1: alpha_last = q_last + pot_last; full argmax once
  float qlo_t = outb[(NT - 1) * NC + l];
  float qhi_t = outb[(NT - 1) * NC + 64 + l];
  float alo_t = qlo_t + potb[(NT - 1) * NC + l];
  float ahi_t = qhi_t + potb[(NT - 1) * NC + 64 + l];
  float m0 = wave_max_to_lane63(fmaxf(alo_t, ahi_t));
  float M0 = __int_as_float(__builtin_amdgcn_readlane(__float_as_int(m0), 63));
  unsigned long long bl = __ballot(alo_t == M0);
  unsigned long long bh = __ballot(ahi_t == M0);
  int tag = bl ? (__ffsll((long long)bl) - 1)
               : (64 + __ffsll((long long)bh) - 1);

  // prefetch rows 1022..1015 (q and pot), precompute alpha
  float cqlo[8], cqhi[8], calo[8], cahi[8];
  float nqlo[8], nqhi[8], nplo[8], nphi[8];
  #pragma unroll
  for (int j = 0; j < 8; ++j) {
    int rw = NT - 2 - j;
    cqlo[j] = outb[rw * NC + l];
    cqhi[j] = outb[rw * NC + 64 + l];
    calo[j] = cqlo[j] + potb[rw * NC + l];
    cahi[j] = cqhi[j] + potb[rw * NC + 64 + l];
  }

  for (int g2 = 0; g2 < 128; ++g2) {
    #pragma unroll
    for (int j = 0; j < 8; ++j) {      // prefetch group g2+1
      int rw = NT - 10 - 8 * g2 - j;
      if (rw < 0) rw = 0;
      nqlo[j] = outb[rw * NC + l];
      nqhi[j] = outb[rw * NC + 64 + l];
      nplo[j] = potb[rw * NC + l];
      nphi[j] = potb[rw * NC + 64 + l];
    }
    #pragma unroll
    for (int j = 0; j < 8; ++j) {
      int t = NT - 1 - 8 * g2 - j;
      if (t >= 1) {
        outb[t * NC + l]      = (l == tag) ? 1.0f : 0.0f;
        outb[t * NC + 64 + l] = (64 + l == tag) ? 1.0f : 0.0f;
        int Mlo = __builtin_amdgcn_readlane(__float_as_int(qlo_t), tag & 63);
        int Mhi = __builtin_amdgcn_readlane(__float_as_int(qhi_t), tag & 63);
        float M = __int_as_float((tag < 64) ? Mlo : Mhi);
        f32x2 tt = tTp[tag * 64 + l];
        float vlo = calo[j] + tt.x;
        float vhi = cahi[j] + tt.y;
        unsigned long long el = __ballot(vlo == M);
        unsigned long long eh = __ballot(vhi == M);
        tag = el ? (__ffsll((long long)el) - 1)
                 : (64 + __ffsll((long long)eh) - 1);
        qlo_t = cqlo[j];
        qhi_t = cqhi[j];
      }
    }
    #pragma unroll
    for (int j = 0; j < 8; ++j) {
      cqlo[j] = nqlo[j]; cqhi[j] = nqhi[j];
      calo[j] = nqlo[j] + nplo[j];
      cahi[j] = nqhi[j] + nphi[j];
    }
  }
  outb[l]      = (l == tag) ? 1.0f : 0.0f;
  outb[64 + l] = (64 + l == tag) ? 1.0f : 0.0f;
}

// ---------------- launch ----------------

extern "C" void kernel_launch(void* const* d_in, const int* in_sizes, int n_in,
                              void* d_out, int out_size, void* d_ws, size_t ws_size,
                              hipStream_t stream) {
  const float* pot   = (const float*)d_in[0];
  const float* trans = (const float*)d_in[1];
  float* out = (float*)d_out;

  constexpr int SMEM = (2 * ABUF + NC * NC) * 4;   // 67072 B
  hipFuncSetAttribute((const void*)crf_fused,
                      hipFuncAttributeMaxDynamicSharedMemorySize, SMEM);

  crf_fused<<<NB, 512, SMEM, stream>>>(pot, trans, out);
}